// Round 2
// baseline (869.632 us; speedup 1.0000x reference)
//
#include <hip/hip_runtime.h>
#include <hip/hip_bf16.h>
#include <stdint.h>

// Problem constants (fixed by the reference)
#define NN   50000
#define RR   50
#define BB   30
#define DIN  64
#define EE   1000000
#define KTOT (BB*DIN + DIN)   // 1984 = 62*32
#define NBW  16               // nodes per workgroup; 50000 = 3125*16 exactly
#define ROWE (KTOT + 8)       // padded LDS row: 1992 elems (3984 B)
#define CPAD 32               // comp row padded 30 -> 32 floats

typedef __attribute__((ext_vector_type(8))) short short8;
typedef __attribute__((ext_vector_type(4))) float floatx4;

#define RFL(x) __builtin_amdgcn_readfirstlane(x)

// ---------------- preprocessing: counting sort of edges by dst ----------------

__global__ void k_hist(const int* __restrict__ dst, const int* __restrict__ et,
                       int* __restrict__ cnt) {
    int e = blockIdx.x * 256 + threadIdx.x;
    if (e < EE) {
        int d = dst[e], r = et[e];
        atomicAdd(&cnt[d * RR + r], 1);
    }
}

// derive dcount from cnt rows (removes 1M atomics from k_hist), then block scan
__global__ void k_scan1(const int* __restrict__ cnt, int* __restrict__ dcount,
                        int* __restrict__ doff, int* __restrict__ bsum) {
    __shared__ int sh[256];
    int t = threadIdx.x;
    int i = blockIdx.x * 256 + t;
    int v = 0;
    if (i < NN) {
        const int* c = cnt + (size_t)i * RR;
#pragma unroll
        for (int r = 0; r < RR; ++r) v += c[r];
        dcount[i] = v;
    }
    sh[t] = v;
    __syncthreads();
    for (int s = 1; s < 256; s <<= 1) {
        int add = (t >= s) ? sh[t - s] : 0;
        __syncthreads();
        sh[t] += add;
        __syncthreads();
    }
    int incl = sh[t];
    if (i < NN) doff[i] = incl - v;
    if (t == 255) bsum[blockIdx.x] = incl;
}

__global__ void k_scan2(int* __restrict__ bsum, int nbv) {
    __shared__ int sh[256];
    int t = threadIdx.x;
    int v = (t < nbv) ? bsum[t] : 0;
    sh[t] = v;
    __syncthreads();
    for (int s = 1; s < 256; s <<= 1) {
        int add = (t >= s) ? sh[t - s] : 0;
        __syncthreads();
        sh[t] += add;
        __syncthreads();
    }
    if (t < nbv) bsum[t] = sh[t] - v;
}

__global__ void k_scan3(int* __restrict__ doff, const int* __restrict__ bsum) {
    int i = blockIdx.x * 256 + threadIdx.x;
    if (i < NN) doff[i] += bsum[blockIdx.x];
}

// records: .x = src | (rel<<16)  (src<65536, rel<50), .y = bits of a = 1/cnt(d,r)
__global__ void k_scatter(const int* __restrict__ src, const int* __restrict__ dst,
                          const int* __restrict__ et, const int* __restrict__ cnt,
                          const int* __restrict__ doff, int* __restrict__ cursor,
                          int2* __restrict__ ep2) {
    int e = blockIdx.x * 256 + threadIdx.x;
    if (e < EE) {
        int d = dst[e], r = et[e], s = src[e];
        int p = doff[d] + atomicAdd(&cursor[d], 1);
        float a = 1.0f / (float)cnt[d * RR + r];
        ep2[p] = make_int2(s | (r << 16), __float_as_int(a));
    }
}

__global__ void k_cast_x(const float* __restrict__ x, __hip_bfloat16* __restrict__ h) {
    int i = blockIdx.x * 256 + threadIdx.x;
    if (i < NN * DIN) h[i] = __float2bfloat16(x[i]);
}

// all 3 layers' comp [R,30] fp32 -> padded [3][R,32] fp32
__global__ void k_prep_comp3(const float* __restrict__ c0, const float* __restrict__ c1,
                             const float* __restrict__ c2, float* __restrict__ cp) {
    int idx = blockIdx.x * 256 + threadIdx.x;
    if (idx < 3 * RR * CPAD) {
        int l = idx / (RR * CPAD);
        int rem = idx - l * (RR * CPAD);
        int r = rem / CPAD, i = rem - r * CPAD;
        const float* c = (l == 0) ? c0 : (l == 1) ? c1 : c2;
        cp[idx] = (i < BB) ? c[r * BB + i] : 0.f;
    }
}

// all 3 layers' transposed bf16 weights:
// wt rows [0,64): layer0; [64,128): layer1; [128,144): layer2 (dout=8, 16 padded rows)
__global__ void k_prep_w3(const float* __restrict__ b0, const float* __restrict__ r0,
                          const float* __restrict__ b1, const float* __restrict__ r1,
                          const float* __restrict__ b2, const float* __restrict__ r2,
                          short* __restrict__ wt) {
    int idx = blockIdx.x * 256 + threadIdx.x;
    if (idx >= 144 * KTOT) return;
    int row = idx / KTOT, k = idx - row * KTOT;
    const float* bs; const float* rt; int o, dout;
    if (row < 64)       { bs = b0; rt = r0; o = row;        dout = 64; }
    else if (row < 128) { bs = b1; rt = r1; o = row - 64;   dout = 64; }
    else                { bs = b2; rt = r2; o = row - 128;  dout = 8;  }
    float v = 0.f;
    if (o < dout)
        v = (k < BB * DIN) ? bs[k * dout + o] : rt[(k - BB * DIN) * dout + o];
    __hip_bfloat16 hb = __float2bfloat16(v);
    wt[idx] = *reinterpret_cast<const short*>(&hb);
}

// ---------------- fused per-layer kernel ----------------
// 512 threads = 8 waves. __launch_bounds__ 2nd arg is MIN BLOCKS PER CU
// (CUDA semantics — verified empirically: (512,4) capped VGPRs at 64 and
// spilled 21 MB to scratch in R1). LDS 63744 B caps us at 2 blocks/CU anyway,
// so (512,2) -> 16 waves/CU, 128-VGPR budget, accA+accB (64 VGPR) fits.
// Phase 1: wave wv owns nodes (wv, wv+8). Both nodes' 4-edge chunk lists
//   (tails included as a=0-masked chunks) form ONE pipelined stream:
//   records for chunk t+2 prefetched (scalar s_load, mask applied at load),
//   gathers for chunk t+1 in flight during chunk t's FMAs. Pipeline never
//   drains between nodes; no serial tail path.
// Phase 2: 8 waves = 4 col-tiles x 2 K-parts (DOUT=64) or 8 K-parts (DOUT=8);
//   partials reduced through LDS with stride-6 layout.

// load+mask 4 records of chunk u (all scalar ops; ghost edges get src=0, a=0)
#define LOADREC(u, q0, q1, q2, q3) do {                                         \
    const int _u  = (u);                                                        \
    const int _b  = (_u < nchA) ? (begA + 4*_u) : (begB + 4*(_u - nchA));       \
    const int _rm = (_u < nchA) ? (cntA - 4*_u) : (cntB - 4*(_u - nchA));       \
    q0 = ep2[_b];     q1 = ep2[_b + 1];                                         \
    q2 = ep2[_b + 2]; q3 = ep2[_b + 3];                                         \
    q1.x = (_rm > 1) ? q1.x : 0;  q1.y = (_rm > 1) ? q1.y : 0;                  \
    q2.x = (_rm > 2) ? q2.x : 0;  q2.y = (_rm > 2) ? q2.y : 0;                  \
    q3.x = (_rm > 3) ? q3.x : 0;  q3.y = (_rm > 3) ? q3.y : 0;                  \
} while (0)

// issue gather for one record (raw bf16 bits; cvt deferred to FMA site)
#define GATH(q) ((unsigned)xin16[(RFL((q).x) & 0xFFFF) * DIN + lane])

// one edge's rank-1 update into ACC (comp row via scalar loads)
#define EDGE_FMA(q, g, ACC) do {                                                \
    const int   _sx = RFL((q).x);                                               \
    const float _a  = __int_as_float(RFL((q).y));                               \
    const floatx4* _c = (const floatx4*)(compP + (_sx >> 16) * CPAD);           \
    const float _g  = __uint_as_float((g) << 16);   /* bf16 -> f32 */           \
    const float _xv = _g * _a;                                                  \
    const floatx4 _w = {_xv, _xv, _xv, _xv};                                    \
    ACC[0] = _c[0] * _w + ACC[0];  ACC[1] = _c[1] * _w + ACC[1];                \
    ACC[2] = _c[2] * _w + ACC[2];  ACC[3] = _c[3] * _w + ACC[3];                \
    ACC[4] = _c[4] * _w + ACC[4];  ACC[5] = _c[5] * _w + ACC[5];                \
    ACC[6] = _c[6] * _w + ACC[6];  ACC[7] = _c[7] * _w + ACC[7];                \
} while (0)

template <int DOUT, bool RELU>
__global__ __launch_bounds__(512, 2)
void k_fused(const __hip_bfloat16* __restrict__ xin,
             const int2* __restrict__ ep2,
             const int* __restrict__ doff, const int* __restrict__ dcount,
             const float* __restrict__ compP,    // [R, 32] fp32 padded
             const short* __restrict__ Wt,       // [DPAD][KTOT] bf16 (transposed)
             const float* __restrict__ bias,     // [DOUT]
             void* __restrict__ outp) {
    __shared__ __align__(16) char smem_raw[NBW * ROWE * 2];   // 63744 B
    auto t_tile = reinterpret_cast<__hip_bfloat16(*)[ROWE]>(smem_raw);
    const unsigned short* xin16 = reinterpret_cast<const unsigned short*>(xin);
    const int tid  = threadIdx.x;
    const int lane = tid & 63;
    const int wv   = RFL(tid >> 6);          // 0..7
    const int node0 = blockIdx.x * NBW;
    const int nA = node0 + wv;
    const int nB = node0 + wv + 8;

    // ---- phase 1: two nodes per wave, unified pipelined chunk stream ----
    {
        floatx4 accA[8], accB[8];
#pragma unroll
        for (int u = 0; u < 8; ++u) {
            accA[u] = (floatx4){0.f, 0.f, 0.f, 0.f};
            accB[u] = (floatx4){0.f, 0.f, 0.f, 0.f};
        }
        // self rows: issue early, consumed at epilogue
        const unsigned selfA = (unsigned)xin16[nA * DIN + lane];
        const unsigned selfB = (unsigned)xin16[nB * DIN + lane];

        const int begA = RFL(doff[nA]), cntA = RFL(dcount[nA]);
        const int begB = RFL(doff[nB]), cntB = RFL(dcount[nB]);
        const int nchA = (cntA + 3) >> 2;
        const int nchB = (cntB + 3) >> 2;
        const int T = nchA + nchB;

        if (T > 0) {
            int2 c0, c1, c2, c3, n0, n1, n2, n3;
            LOADREC(0, c0, c1, c2, c3);
            unsigned g0 = GATH(c0), g1 = GATH(c1), g2 = GATH(c2), g3 = GATH(c3);
            { const int u1 = (1 < T) ? 1 : 0; LOADREC(u1, n0, n1, n2, n3); }

            for (int t = 0; t < T; ++t) {
                // prefetch records for chunk t+2 (clamped)
                int2 p0, p1, p2, p3;
                { const int u2 = (t + 2 < T) ? (t + 2) : (T - 1);
                  LOADREC(u2, p0, p1, p2, p3); }
                // issue gathers for chunk t+1
                unsigned h0 = GATH(n0), h1 = GATH(n1), h2 = GATH(n2), h3 = GATH(n3);
                // FMA chunk t into the owning node's accumulator (uniform branch)
                if (t < nchA) {
                    EDGE_FMA(c0, g0, accA); EDGE_FMA(c1, g1, accA);
                    EDGE_FMA(c2, g2, accA); EDGE_FMA(c3, g3, accA);
                } else {
                    EDGE_FMA(c0, g0, accB); EDGE_FMA(c1, g1, accB);
                    EDGE_FMA(c2, g2, accB); EDGE_FMA(c3, g3, accB);
                }
                // rotate pipeline
                c0 = n0; c1 = n1; c2 = n2; c3 = n3;
                n0 = p0; n1 = p1; n2 = p2; n3 = p3;
                g0 = h0; g1 = h1; g2 = h2; g3 = h3;
            }
        }
        // epilogue: write both rows
#pragma unroll
        for (int b = 0; b < BB; ++b)
            t_tile[wv][b * DIN + lane] = __float2bfloat16(accA[b >> 2][b & 3]);
        t_tile[wv][BB * DIN + lane] =
            __float2bfloat16(__uint_as_float(selfA << 16));
#pragma unroll
        for (int b = 0; b < BB; ++b)
            t_tile[wv + 8][b * DIN + lane] = __float2bfloat16(accB[b >> 2][b & 3]);
        t_tile[wv + 8][BB * DIN + lane] =
            __float2bfloat16(__uint_as_float(selfB << 16));
    }
    __syncthreads();

    // ---- phase 2: MFMA 16x16x32 bf16, K = 1984 (62 steps) over 8 waves ----
    const int m = lane & 15;
    const int q = lane >> 4;
    int kk0, nsteps, col_base, kpart;
    if (DOUT == 64) {
        kpart = wv >> 2;                 // 0..1
        col_base = (wv & 3) * 16;
        kk0    = kpart * 31;
        nsteps = 31;
    } else {
        kpart = wv;                      // 0..7
        col_base = 0;
        kk0    = (kpart < 7) ? kpart * 8 : 55;   // 6*8=48, then 7+7
        nsteps = (kpart < 6) ? 8 : 7;
    }
    const __hip_bfloat16* arow = &t_tile[m][q * 8];
    const short* brow = Wt + (size_t)(col_base + m) * KTOT + q * 8;

    floatx4 acc0 = {0.f, 0.f, 0.f, 0.f};
    floatx4 acc1 = {0.f, 0.f, 0.f, 0.f};
    int s = 0;
    for (; s + 2 <= nsteps; s += 2) {
        const int kk = kk0 + s;
        short8 a0 = *reinterpret_cast<const short8*>(arow + kk * 32);
        short8 b0 = *reinterpret_cast<const short8*>(brow + kk * 32);
        short8 a1 = *reinterpret_cast<const short8*>(arow + (kk + 1) * 32);
        short8 b1 = *reinterpret_cast<const short8*>(brow + (kk + 1) * 32);
        acc0 = __builtin_amdgcn_mfma_f32_16x16x32_bf16(a0, b0, acc0, 0, 0, 0);
        acc1 = __builtin_amdgcn_mfma_f32_16x16x32_bf16(a1, b1, acc1, 0, 0, 0);
    }
    if (s < nsteps) {
        const int kk = kk0 + s;
        short8 a0 = *reinterpret_cast<const short8*>(arow + kk * 32);
        short8 b0 = *reinterpret_cast<const short8*>(brow + kk * 32);
        acc0 = __builtin_amdgcn_mfma_f32_16x16x32_bf16(a0, b0, acc0, 0, 0, 0);
    }
    floatx4 P = acc0 + acc1;

    __syncthreads();                       // all t_tile reads done
    float* red = (float*)smem_raw;         // reuse LDS; stride-6 layout

    if (DOUT == 64) {
        // 2 K-parts per col group; part 1 writes, part 0 reduces
        if (kpart == 1) {
            const int off = ((wv & 3) * 64 + lane) * 6;
            red[off] = P[0]; red[off + 1] = P[1]; red[off + 2] = P[2]; red[off + 3] = P[3];
        }
        __syncthreads();
        if (kpart == 0) {
            const int off = ((wv & 3) * 64 + lane) * 6;
            P[0] += red[off]; P[1] += red[off + 1];
            P[2] += red[off + 2]; P[3] += red[off + 3];
            const int o = col_base + m;
            const float bi = bias[o];
#pragma unroll
            for (int r = 0; r < 4; ++r) {
                const int n = node0 + q * 4 + r;
                float v = P[r] + bi;
                if (RELU) {
                    v = fmaxf(v, 0.f);
                    reinterpret_cast<__hip_bfloat16*>(outp)[(size_t)n * DOUT + o] =
                        __float2bfloat16(v);
                } else {
                    reinterpret_cast<float*>(outp)[(size_t)n * DOUT + o] = v;
                }
            }
        }
    } else {
        if (kpart > 0) {
            const int off = ((kpart - 1) * 64 + lane) * 6;
            red[off] = P[0]; red[off + 1] = P[1]; red[off + 2] = P[2]; red[off + 3] = P[3];
        }
        __syncthreads();
        if (kpart == 0) {
#pragma unroll
            for (int w = 0; w < 7; ++w) {
                const int off = (w * 64 + lane) * 6;
                P[0] += red[off]; P[1] += red[off + 1];
                P[2] += red[off + 2]; P[3] += red[off + 3];
            }
            if (m < DOUT) {
                const int o = m;
                const float bi = bias[o];
#pragma unroll
                for (int r = 0; r < 4; ++r) {
                    const int n = node0 + q * 4 + r;
                    reinterpret_cast<float*>(outp)[(size_t)n * DOUT + o] = P[r] + bi;
                }
            }
        }
    }
}

// ---------------- log_softmax over C=8 ----------------
__global__ void k_lsm(const float* __restrict__ pre, float* __restrict__ out) {
    int n = blockIdx.x * 256 + threadIdx.x;
    if (n < NN) {
        float v[8];
        float mx = -1e30f;
#pragma unroll
        for (int c = 0; c < 8; ++c) { v[c] = pre[n * 8 + c]; mx = fmaxf(mx, v[c]); }
        float s = 0.f;
#pragma unroll
        for (int c = 0; c < 8; ++c) s += expf(v[c] - mx);
        float ls = logf(s);
#pragma unroll
        for (int c = 0; c < 8; ++c) out[n * 8 + c] = v[c] - mx - ls;
    }
}

// ---------------- launch ----------------
extern "C" void kernel_launch(void* const* d_in, const int* in_sizes, int n_in,
                              void* d_out, int out_size, void* d_ws, size_t ws_size,
                              hipStream_t stream) {
    const float* x     = (const float*)d_in[0];
    const int*   eidx  = (const int*)d_in[1];
    const int*   etype = (const int*)d_in[2];
    const float* bases0 = (const float*)d_in[3];
    const float* comp0  = (const float*)d_in[4];
    const float* root0  = (const float*)d_in[5];
    const float* bias0  = (const float*)d_in[6];
    const float* bases1 = (const float*)d_in[7];
    const float* comp1  = (const float*)d_in[8];
    const float* root1  = (const float*)d_in[9];
    const float* bias1  = (const float*)d_in[10];
    const float* bases2 = (const float*)d_in[11];
    const float* comp2  = (const float*)d_in[12];
    const float* root2  = (const float*)d_in[13];
    const float* bias2  = (const float*)d_in[14];
    const int* srcp = eidx;
    const int* dstp = eidx + EE;

    char* p = (char*)d_ws;
    auto carve = [&](size_t bytes) -> char* {
        char* r = p;
        p += (bytes + 255) & ~(size_t)255;
        return r;
    };
    int*  cnt    = (int*)carve((size_t)NN * RR * sizeof(int));   // 10 MB
    int*  dcount = (int*)carve((size_t)NN * sizeof(int));
    int*  cursor = (int*)carve((size_t)NN * sizeof(int));
    int*  doff   = (int*)carve((size_t)NN * sizeof(int));
    int*  bsum   = (int*)carve(256 * sizeof(int));
    int2* ep2    = (int2*)carve((size_t)(EE + 8) * sizeof(int2)); // 8 MB (+overrun pad)
    __hip_bfloat16* h0 = (__hip_bfloat16*)carve((size_t)NN * DIN * 2);
    __hip_bfloat16* h1 = (__hip_bfloat16*)carve((size_t)NN * DIN * 2);
    __hip_bfloat16* h2 = (__hip_bfloat16*)carve((size_t)NN * DIN * 2);
    float* pre = (float*)carve((size_t)NN * 8 * sizeof(float));
    short* wtA = (short*)carve((size_t)144 * KTOT * sizeof(short));  // 3 layers stacked
    float* cpA = (float*)carve((size_t)3 * RR * CPAD * sizeof(float));

    // cnt, dcount, cursor are adjacent in the carve order -> one memset
    hipMemsetAsync(cnt, 0, (size_t)NN * (RR + 2) * sizeof(int) + 512, stream);

    const int EB = (EE + 255) / 256;   // 3907
    const int NB = (NN + 255) / 256;   // 196
    k_hist<<<EB, 256, 0, stream>>>(dstp, etype, cnt);
    k_scan1<<<NB, 256, 0, stream>>>(cnt, dcount, doff, bsum);
    k_scan2<<<1, 256, 0, stream>>>(bsum, NB);
    k_scan3<<<NB, 256, 0, stream>>>(doff, bsum);
    k_scatter<<<EB, 256, 0, stream>>>(srcp, dstp, etype, cnt, doff, cursor, ep2);
    k_cast_x<<<(NN * DIN + 255) / 256, 256, 0, stream>>>(x, h0);
    k_prep_comp3<<<(3 * RR * CPAD + 255) / 256, 256, 0, stream>>>(comp0, comp1, comp2, cpA);
    k_prep_w3<<<(144 * KTOT + 255) / 256, 256, 0, stream>>>(bases0, root0, bases1, root1,
                                                            bases2, root2, wtA);

    short* wt0 = wtA;
    short* wt1 = wtA + (size_t)64 * KTOT;
    short* wt2 = wtA + (size_t)128 * KTOT;
    float* cp0 = cpA;
    float* cp1 = cpA + RR * CPAD;
    float* cp2 = cpA + 2 * RR * CPAD;

    const int NF = NN / NBW;   // 3125 (exact)
    k_fused<64, true ><<<NF, 512, 0, stream>>>(h0, ep2, doff, dcount, cp0, wt0, bias0, (void*)h1);
    k_fused<64, true ><<<NF, 512, 0, stream>>>(h1, ep2, doff, dcount, cp1, wt1, bias1, (void*)h2);
    k_fused<8,  false><<<NF, 512, 0, stream>>>(h2, ep2, doff, dcount, cp2, wt2, bias2, (void*)pre);
    k_lsm<<<NB, 256, 0, stream>>>(pre, (float*)d_out);
}

// Round 3
// 829.278 us; speedup vs baseline: 1.0487x; 1.0487x over previous
//
#include <hip/hip_runtime.h>
#include <hip/hip_bf16.h>
#include <stdint.h>

// Problem constants (fixed by the reference)
#define NN   50000
#define RR   50
#define BB   30
#define DIN  64
#define EE   1000000
#define KTOT (BB*DIN + DIN)   // 1984 = 62*32
#define NBW  16               // nodes per workgroup; 50000 = 3125*16 exactly
#define ROWE (KTOT + 8)       // padded LDS row: 1992 elems (3984 B)
#define CPAD 32               // comp row padded 30 -> 32 floats

typedef __attribute__((ext_vector_type(8))) short short8;
typedef __attribute__((ext_vector_type(4))) float floatx4;

#define RFL(x) __builtin_amdgcn_readfirstlane(x)

// ---------------- preprocessing: counting sort of edges by dst ----------------

__global__ void k_hist(const int* __restrict__ dst, const int* __restrict__ et,
                       int* __restrict__ cnt) {
    int e = blockIdx.x * 256 + threadIdx.x;
    if (e < EE) {
        int d = dst[e], r = et[e];
        atomicAdd(&cnt[d * RR + r], 1);
    }
}

// derive dcount from cnt rows (removes 1M atomics from k_hist), then block scan
__global__ void k_scan1(const int* __restrict__ cnt, int* __restrict__ dcount,
                        int* __restrict__ doff, int* __restrict__ bsum) {
    __shared__ int sh[256];
    int t = threadIdx.x;
    int i = blockIdx.x * 256 + t;
    int v = 0;
    if (i < NN) {
        const int* c = cnt + (size_t)i * RR;
#pragma unroll
        for (int r = 0; r < RR; ++r) v += c[r];
        dcount[i] = v;
    }
    sh[t] = v;
    __syncthreads();
    for (int s = 1; s < 256; s <<= 1) {
        int add = (t >= s) ? sh[t - s] : 0;
        __syncthreads();
        sh[t] += add;
        __syncthreads();
    }
    int incl = sh[t];
    if (i < NN) doff[i] = incl - v;
    if (t == 255) bsum[blockIdx.x] = incl;
}

__global__ void k_scan2(int* __restrict__ bsum, int nbv) {
    __shared__ int sh[256];
    int t = threadIdx.x;
    int v = (t < nbv) ? bsum[t] : 0;
    sh[t] = v;
    __syncthreads();
    for (int s = 1; s < 256; s <<= 1) {
        int add = (t >= s) ? sh[t - s] : 0;
        __syncthreads();
        sh[t] += add;
        __syncthreads();
    }
    if (t < nbv) bsum[t] = sh[t] - v;
}

__global__ void k_scan3(int* __restrict__ doff, const int* __restrict__ bsum) {
    int i = blockIdx.x * 256 + threadIdx.x;
    if (i < NN) doff[i] += bsum[blockIdx.x];
}

// records: .x = src | (rel<<16)  (src<65536, rel<50), .y = bits of a = 1/cnt(d,r)
__global__ void k_scatter(const int* __restrict__ src, const int* __restrict__ dst,
                          const int* __restrict__ et, const int* __restrict__ cnt,
                          const int* __restrict__ doff, int* __restrict__ cursor,
                          int2* __restrict__ ep2) {
    int e = blockIdx.x * 256 + threadIdx.x;
    if (e < EE) {
        int d = dst[e], r = et[e], s = src[e];
        int p = doff[d] + atomicAdd(&cursor[d], 1);
        float a = 1.0f / (float)cnt[d * RR + r];
        ep2[p] = make_int2(s | (r << 16), __float_as_int(a));
    }
}

// ---------------- degree counting-sort (descending) for wave balance ----------
// Block b processes 16 consecutive nodes of the degree-sorted order: all 16
// waves in a block then have near-identical edge counts -> no barrier idle.

__global__ void k_deghist(const int* __restrict__ dcount, int* __restrict__ dbin) {
    int i = blockIdx.x * 256 + threadIdx.x;
    if (i < NN) {
        int d = dcount[i]; d = (d > 255) ? 255 : d;
        atomicAdd(&dbin[255 - d], 1);     // descending degree
    }
}

__global__ void k_degscan(int* __restrict__ dbin) {   // exclusive scan of 256
    __shared__ int sh[256];
    int t = threadIdx.x;
    int v = dbin[t];
    sh[t] = v;
    __syncthreads();
    for (int s = 1; s < 256; s <<= 1) {
        int add = (t >= s) ? sh[t - s] : 0;
        __syncthreads();
        sh[t] += add;
        __syncthreads();
    }
    dbin[t] = sh[t] - v;
}

__global__ void k_degscatter(const int* __restrict__ dcount, const int* __restrict__ dbin,
                             int* __restrict__ dcur, int* __restrict__ order) {
    int i = blockIdx.x * 256 + threadIdx.x;
    if (i < NN) {
        int d = dcount[i]; d = (d > 255) ? 255 : d;
        int b = 255 - d;
        int pos = dbin[b] + atomicAdd(&dcur[b], 1);
        order[pos] = i;
    }
}

__global__ void k_cast_x(const float* __restrict__ x, __hip_bfloat16* __restrict__ h) {
    int i = blockIdx.x * 256 + threadIdx.x;
    if (i < NN * DIN) h[i] = __float2bfloat16(x[i]);
}

// all 3 layers' comp [R,30] fp32 -> padded [3][R,32] fp32
__global__ void k_prep_comp3(const float* __restrict__ c0, const float* __restrict__ c1,
                             const float* __restrict__ c2, float* __restrict__ cp) {
    int idx = blockIdx.x * 256 + threadIdx.x;
    if (idx < 3 * RR * CPAD) {
        int l = idx / (RR * CPAD);
        int rem = idx - l * (RR * CPAD);
        int r = rem / CPAD, i = rem - r * CPAD;
        const float* c = (l == 0) ? c0 : (l == 1) ? c1 : c2;
        cp[idx] = (i < BB) ? c[r * BB + i] : 0.f;
    }
}

// all 3 layers' transposed bf16 weights:
// wt rows [0,64): layer0; [64,128): layer1; [128,144): layer2 (dout=8, 16 padded rows)
__global__ void k_prep_w3(const float* __restrict__ b0, const float* __restrict__ r0,
                          const float* __restrict__ b1, const float* __restrict__ r1,
                          const float* __restrict__ b2, const float* __restrict__ r2,
                          short* __restrict__ wt) {
    int idx = blockIdx.x * 256 + threadIdx.x;
    if (idx >= 144 * KTOT) return;
    int row = idx / KTOT, k = idx - row * KTOT;
    const float* bs; const float* rt; int o, dout;
    if (row < 64)       { bs = b0; rt = r0; o = row;        dout = 64; }
    else if (row < 128) { bs = b1; rt = r1; o = row - 64;   dout = 64; }
    else                { bs = b2; rt = r2; o = row - 128;  dout = 8;  }
    float v = 0.f;
    if (o < dout)
        v = (k < BB * DIN) ? bs[k * dout + o] : rt[(k - BB * DIN) * dout + o];
    __hip_bfloat16 hb = __float2bfloat16(v);
    wt[idx] = *reinterpret_cast<const short*>(&hb);
}

// ---------------- fused per-layer kernel ----------------
// 1024 threads = 16 waves, 2 blocks/CU (LDS-capped) -> 32 waves/CU (the proven
// R0 configuration; R1/R2 showed dropping occupancy for per-wave pipelining
// regresses). Wave wv owns tile row wv = degree-sorted node order[node0+wv];
// all waves in a block have near-equal degree -> minimal barrier idle.
// Phase 1: 4-edge chunks in a 3-stage pipeline (records 2 ahead via s_load,
// gathers 1 ahead). Phase 2: 16 waves = 4 col-tiles x 4 K-parts (DOUT=64)
// or 16 K-parts (DOUT=8); partials reduced through LDS, stride-6 layout.
template <int DOUT, bool RELU>
__global__ __launch_bounds__(1024, 8)
void k_fused(const __hip_bfloat16* __restrict__ xin,
             const int2* __restrict__ ep2,
             const int* __restrict__ doff, const int* __restrict__ dcount,
             const int* __restrict__ order,
             const float* __restrict__ compP,    // [R, 32] fp32 padded
             const short* __restrict__ Wt,       // [DPAD][KTOT] bf16 (transposed)
             const float* __restrict__ bias,     // [DOUT]
             void* __restrict__ outp) {
    __shared__ __align__(16) char smem_raw[NBW * ROWE * 2];   // 63744 B
    auto t_tile = reinterpret_cast<__hip_bfloat16(*)[ROWE]>(smem_raw);
    const unsigned short* xin16 = reinterpret_cast<const unsigned short*>(xin);
    const int tid  = threadIdx.x;
    const int lane = tid & 63;
    const int wv   = RFL(tid >> 6);          // 0..15
    const int node0 = blockIdx.x * NBW;

    // ---- phase 1: one node per wave, pipelined 4-edge chunks ----
    {
        const int j = wv;
        const int n = RFL(order[node0 + j]);
        floatx4 acc[8];
#pragma unroll
        for (int u = 0; u < 8; ++u) acc[u] = (floatx4){0.f, 0.f, 0.f, 0.f};
        const int beg = RFL(doff[n]), cnt = RFL(dcount[n]);
        const int nch = cnt >> 2;             // full 4-edge chunks

        if (nch > 0) {
            // current-chunk records (SGPRs)
            int2 cr0 = ep2[beg + 0], cr1 = ep2[beg + 1];
            int2 cr2 = ep2[beg + 2], cr3 = ep2[beg + 3];
            // gathers for chunk 0 (in flight)
            float g0 = __bfloat162float(xin[(RFL(cr0.x) & 0xFFFF) * DIN + lane]);
            float g1 = __bfloat162float(xin[(RFL(cr1.x) & 0xFFFF) * DIN + lane]);
            float g2 = __bfloat162float(xin[(RFL(cr2.x) & 0xFFFF) * DIN + lane]);
            float g3 = __bfloat162float(xin[(RFL(cr3.x) & 0xFFFF) * DIN + lane]);
            // next-chunk records (clamped)
            const int b1 = beg + ((1 < nch) ? 4 : 0);
            int2 nr0 = ep2[b1 + 0], nr1 = ep2[b1 + 1];
            int2 nr2 = ep2[b1 + 2], nr3 = ep2[b1 + 3];

            for (int c = 0; c < nch; ++c) {
                // prefetch records for chunk c+2 (clamped; uniform s_load)
                const int cc = (c + 2 < nch) ? (c + 2) : (nch - 1);
                const int bp = beg + 4 * cc;
                int2 p0 = ep2[bp + 0], p1 = ep2[bp + 1];
                int2 p2 = ep2[bp + 2], p3 = ep2[bp + 3];
                // issue gathers for chunk c+1 (records already in SGPRs)
                float h0 = __bfloat162float(xin[(RFL(nr0.x) & 0xFFFF) * DIN + lane]);
                float h1 = __bfloat162float(xin[(RFL(nr1.x) & 0xFFFF) * DIN + lane]);
                float h2 = __bfloat162float(xin[(RFL(nr2.x) & 0xFFFF) * DIN + lane]);
                float h3 = __bfloat162float(xin[(RFL(nr3.x) & 0xFFFF) * DIN + lane]);
                // FMA chunk c (waits only on chunk c's gathers)
                {
                    const int sx0 = RFL(cr0.x);
                    const float a0 = __int_as_float(RFL(cr0.y));
                    const floatx4* q0 = (const floatx4*)(compP + (sx0 >> 16) * CPAD);
                    const float xv0 = g0 * a0;
                    const floatx4 w0 = {xv0, xv0, xv0, xv0};
#pragma unroll
                    for (int u = 0; u < 8; ++u) acc[u] = q0[u] * w0 + acc[u];
                    const int sx1 = RFL(cr1.x);
                    const float a1 = __int_as_float(RFL(cr1.y));
                    const floatx4* q1 = (const floatx4*)(compP + (sx1 >> 16) * CPAD);
                    const float xv1 = g1 * a1;
                    const floatx4 w1 = {xv1, xv1, xv1, xv1};
#pragma unroll
                    for (int u = 0; u < 8; ++u) acc[u] = q1[u] * w1 + acc[u];
                    const int sx2 = RFL(cr2.x);
                    const float a2 = __int_as_float(RFL(cr2.y));
                    const floatx4* q2 = (const floatx4*)(compP + (sx2 >> 16) * CPAD);
                    const float xv2 = g2 * a2;
                    const floatx4 w2 = {xv2, xv2, xv2, xv2};
#pragma unroll
                    for (int u = 0; u < 8; ++u) acc[u] = q2[u] * w2 + acc[u];
                    const int sx3 = RFL(cr3.x);
                    const float a3 = __int_as_float(RFL(cr3.y));
                    const floatx4* q3 = (const floatx4*)(compP + (sx3 >> 16) * CPAD);
                    const float xv3 = g3 * a3;
                    const floatx4 w3 = {xv3, xv3, xv3, xv3};
#pragma unroll
                    for (int u = 0; u < 8; ++u) acc[u] = q3[u] * w3 + acc[u];
                }
                // rotate pipeline
                cr0 = nr0; cr1 = nr1; cr2 = nr2; cr3 = nr3;
                nr0 = p0;  nr1 = p1;  nr2 = p2;  nr3 = p3;
                g0 = h0; g1 = h1; g2 = h2; g3 = h3;
            }
        }
        // tail edges [nch*4, cnt): serial
        for (int e = nch * 4; e < cnt; ++e) {
            int2 ep = ep2[beg + e];
            const int sx = RFL(ep.x);
            const float a = __int_as_float(RFL(ep.y));
            const float xv = __bfloat162float(xin[(sx & 0xFFFF) * DIN + lane]) * a;
            const floatx4* c = (const floatx4*)(compP + (sx >> 16) * CPAD);
            const floatx4 w = {xv, xv, xv, xv};
#pragma unroll
            for (int u = 0; u < 8; ++u) acc[u] = c[u] * w + acc[u];
        }
        const float xself = __bfloat162float(xin[n * DIN + lane]);
#pragma unroll
        for (int b = 0; b < BB; ++b)
            t_tile[j][b * DIN + lane] = __float2bfloat16(acc[b >> 2][b & 3]);
        t_tile[j][BB * DIN + lane] = __float2bfloat16(xself);
    }
    __syncthreads();

    // ---- phase 2: MFMA 16x16x32 bf16, K = 1984 (62 steps) over 16 waves ----
    const int m = lane & 15;
    const int q = lane >> 4;
    int kk0, nsteps, col_base, kpart;
    if (DOUT == 64) {
        kpart = wv >> 2;                 // 0..3
        col_base = (wv & 3) * 16;
        kk0    = (kpart <= 1) ? kpart * 16 : (kpart == 2 ? 32 : 47);
        nsteps = (kpart <= 1) ? 16 : 15;
    } else {
        kpart = wv;                      // 0..15
        col_base = 0;
        kk0    = (kpart < 14) ? kpart * 4 : (kpart == 14 ? 56 : 59);
        nsteps = (kpart < 14) ? 4 : 3;
    }
    const __hip_bfloat16* arow = &t_tile[m][q * 8];
    const short* brow = Wt + (size_t)(col_base + m) * KTOT + q * 8;

    floatx4 acc0 = {0.f, 0.f, 0.f, 0.f};
    floatx4 acc1 = {0.f, 0.f, 0.f, 0.f};
    int s = 0;
    for (; s + 2 <= nsteps; s += 2) {
        const int kk = kk0 + s;
        short8 a0 = *reinterpret_cast<const short8*>(arow + kk * 32);
        short8 b0 = *reinterpret_cast<const short8*>(brow + kk * 32);
        short8 a1 = *reinterpret_cast<const short8*>(arow + (kk + 1) * 32);
        short8 b1 = *reinterpret_cast<const short8*>(brow + (kk + 1) * 32);
        acc0 = __builtin_amdgcn_mfma_f32_16x16x32_bf16(a0, b0, acc0, 0, 0, 0);
        acc1 = __builtin_amdgcn_mfma_f32_16x16x32_bf16(a1, b1, acc1, 0, 0, 0);
    }
    if (s < nsteps) {
        const int kk = kk0 + s;
        short8 a0 = *reinterpret_cast<const short8*>(arow + kk * 32);
        short8 b0 = *reinterpret_cast<const short8*>(brow + kk * 32);
        acc0 = __builtin_amdgcn_mfma_f32_16x16x32_bf16(a0, b0, acc0, 0, 0, 0);
    }
    floatx4 P = acc0 + acc1;

    __syncthreads();                       // all t_tile reads done
    float* red = (float*)smem_raw;         // reuse LDS; stride-6 layout

    if (DOUT == 64) {
        // 4 K-parts per col group; parts 1..3 write, part 0 reduces
        if (kpart > 0) {
            const int slot = (wv & 3) * 3 + (kpart - 1);   // 0..11
            const int off = (slot * 64 + lane) * 6;
            red[off] = P[0]; red[off + 1] = P[1]; red[off + 2] = P[2]; red[off + 3] = P[3];
        }
        __syncthreads();
        if (kpart == 0) {
#pragma unroll
            for (int t = 0; t < 3; ++t) {
                const int off = (((wv & 3) * 3 + t) * 64 + lane) * 6;
                P[0] += red[off]; P[1] += red[off + 1];
                P[2] += red[off + 2]; P[3] += red[off + 3];
            }
            const int o = col_base + m;
            const float bi = bias[o];
#pragma unroll
            for (int r = 0; r < 4; ++r) {
                const int n = order[node0 + q * 4 + r];
                float v = P[r] + bi;
                if (RELU) {
                    v = fmaxf(v, 0.f);
                    reinterpret_cast<__hip_bfloat16*>(outp)[(size_t)n * DOUT + o] =
                        __float2bfloat16(v);
                } else {
                    reinterpret_cast<float*>(outp)[(size_t)n * DOUT + o] = v;
                }
            }
        }
    } else {
        if (kpart > 0) {
            const int off = ((kpart - 1) * 64 + lane) * 6;
            red[off] = P[0]; red[off + 1] = P[1]; red[off + 2] = P[2]; red[off + 3] = P[3];
        }
        __syncthreads();
        if (kpart == 0) {
#pragma unroll
            for (int w = 0; w < 15; ++w) {
                const int off = (w * 64 + lane) * 6;
                P[0] += red[off]; P[1] += red[off + 1];
                P[2] += red[off + 2]; P[3] += red[off + 3];
            }
            if (m < DOUT) {
                const int o = m;
                const float bi = bias[o];
#pragma unroll
                for (int r = 0; r < 4; ++r) {
                    const int n = order[node0 + q * 4 + r];
                    reinterpret_cast<float*>(outp)[(size_t)n * DOUT + o] = P[r] + bi;
                }
            }
        }
    }
}

// ---------------- log_softmax over C=8 ----------------
__global__ void k_lsm(const float* __restrict__ pre, float* __restrict__ out) {
    int n = blockIdx.x * 256 + threadIdx.x;
    if (n < NN) {
        float v[8];
        float mx = -1e30f;
#pragma unroll
        for (int c = 0; c < 8; ++c) { v[c] = pre[n * 8 + c]; mx = fmaxf(mx, v[c]); }
        float s = 0.f;
#pragma unroll
        for (int c = 0; c < 8; ++c) s += expf(v[c] - mx);
        float ls = logf(s);
#pragma unroll
        for (int c = 0; c < 8; ++c) out[n * 8 + c] = v[c] - mx - ls;
    }
}

// ---------------- launch ----------------
extern "C" void kernel_launch(void* const* d_in, const int* in_sizes, int n_in,
                              void* d_out, int out_size, void* d_ws, size_t ws_size,
                              hipStream_t stream) {
    const float* x     = (const float*)d_in[0];
    const int*   eidx  = (const int*)d_in[1];
    const int*   etype = (const int*)d_in[2];
    const float* bases0 = (const float*)d_in[3];
    const float* comp0  = (const float*)d_in[4];
    const float* root0  = (const float*)d_in[5];
    const float* bias0  = (const float*)d_in[6];
    const float* bases1 = (const float*)d_in[7];
    const float* comp1  = (const float*)d_in[8];
    const float* root1  = (const float*)d_in[9];
    const float* bias1  = (const float*)d_in[10];
    const float* bases2 = (const float*)d_in[11];
    const float* comp2  = (const float*)d_in[12];
    const float* root2  = (const float*)d_in[13];
    const float* bias2  = (const float*)d_in[14];
    const int* srcp = eidx;
    const int* dstp = eidx + EE;

    char* p = (char*)d_ws;
    auto carve = [&](size_t bytes) -> char* {
        char* r = p;
        p += (bytes + 255) & ~(size_t)255;
        return r;
    };
    int*  cnt    = (int*)carve((size_t)NN * RR * sizeof(int));   // 10 MB
    int*  dcount = (int*)carve((size_t)NN * sizeof(int));
    int*  cursor = (int*)carve((size_t)NN * sizeof(int));
    int*  doff   = (int*)carve((size_t)NN * sizeof(int));
    int*  bsum   = (int*)carve(256 * sizeof(int));
    int*  dbin   = (int*)carve(256 * sizeof(int));
    int*  dcur   = (int*)carve(256 * sizeof(int));
    int*  order  = (int*)carve((size_t)NN * sizeof(int));
    int2* ep2    = (int2*)carve((size_t)(EE + 8) * sizeof(int2)); // 8 MB (+pad)
    __hip_bfloat16* h0 = (__hip_bfloat16*)carve((size_t)NN * DIN * 2);
    __hip_bfloat16* h1 = (__hip_bfloat16*)carve((size_t)NN * DIN * 2);
    __hip_bfloat16* h2 = (__hip_bfloat16*)carve((size_t)NN * DIN * 2);
    float* pre = (float*)carve((size_t)NN * 8 * sizeof(float));
    short* wtA = (short*)carve((size_t)144 * KTOT * sizeof(short));  // 3 layers stacked
    float* cpA = (float*)carve((size_t)3 * RR * CPAD * sizeof(float));

    // cnt, dcount, cursor are adjacent in the carve order -> one memset
    hipMemsetAsync(cnt, 0, (size_t)NN * (RR + 2) * sizeof(int) + 512, stream);
    // dbin, dcur adjacent (each carved to 1024 B)
    hipMemsetAsync(dbin, 0, 2048, stream);

    const int EB = (EE + 255) / 256;   // 3907
    const int NB = (NN + 255) / 256;   // 196
    k_hist<<<EB, 256, 0, stream>>>(dstp, etype, cnt);
    k_scan1<<<NB, 256, 0, stream>>>(cnt, dcount, doff, bsum);
    k_scan2<<<1, 256, 0, stream>>>(bsum, NB);
    k_scan3<<<NB, 256, 0, stream>>>(doff, bsum);
    k_scatter<<<EB, 256, 0, stream>>>(srcp, dstp, etype, cnt, doff, cursor, ep2);
    k_deghist<<<NB, 256, 0, stream>>>(dcount, dbin);
    k_degscan<<<1, 256, 0, stream>>>(dbin);
    k_degscatter<<<NB, 256, 0, stream>>>(dcount, dbin, dcur, order);
    k_cast_x<<<(NN * DIN + 255) / 256, 256, 0, stream>>>(x, h0);
    k_prep_comp3<<<(3 * RR * CPAD + 255) / 256, 256, 0, stream>>>(comp0, comp1, comp2, cpA);
    k_prep_w3<<<(144 * KTOT + 255) / 256, 256, 0, stream>>>(bases0, root0, bases1, root1,
                                                            bases2, root2, wtA);

    short* wt0 = wtA;
    short* wt1 = wtA + (size_t)64 * KTOT;
    short* wt2 = wtA + (size_t)128 * KTOT;
    float* cp0 = cpA;
    float* cp1 = cpA + RR * CPAD;
    float* cp2 = cpA + 2 * RR * CPAD;

    const int NF = NN / NBW;   // 3125 (exact)
    k_fused<64, true ><<<NF, 1024, 0, stream>>>(h0, ep2, doff, dcount, order, cp0, wt0, bias0, (void*)h1);
    k_fused<64, true ><<<NF, 1024, 0, stream>>>(h1, ep2, doff, dcount, order, cp1, wt1, bias1, (void*)h2);
    k_fused<8,  false><<<NF, 1024, 0, stream>>>(h2, ep2, doff, dcount, order, cp2, wt2, bias2, (void*)pre);
    k_lsm<<<NB, 256, 0, stream>>>(pre, (float*)d_out);
}

// Round 4
// 586.393 us; speedup vs baseline: 1.4830x; 1.4142x over previous
//
#include <hip/hip_runtime.h>
#include <hip/hip_bf16.h>
#include <hip/hip_fp16.h>
#include <stdint.h>

// Problem constants (fixed by the reference)
#define NN   50000
#define RR   50
#define BB   30
#define DIN  64
#define EE   1000000
#define KTOT (BB*DIN + DIN)   // 1984 = 62*32
#define NBW  16               // nodes per workgroup; 50000 = 3125*16 exactly
#define ROWE (KTOT + 8)       // padded LDS row: 1992 elems (3984 B)
#define CPAD 32               // comp row padded 30 -> 32 halves (64 B)

typedef __attribute__((ext_vector_type(8))) short short8;
typedef __attribute__((ext_vector_type(4))) float floatx4;

#define RFL(x) __builtin_amdgcn_readfirstlane(x)

// ---------------- preprocessing: counting sort of edges by dst ----------------

__global__ void k_hist(const int* __restrict__ dst, const int* __restrict__ et,
                       int* __restrict__ cnt) {
    int e = blockIdx.x * 256 + threadIdx.x;
    if (e < EE) {
        int d = dst[e], r = et[e];
        atomicAdd(&cnt[d * RR + r], 1);
    }
}

// derive dcount from cnt rows, then block scan
__global__ void k_scan1(const int* __restrict__ cnt, int* __restrict__ dcount,
                        int* __restrict__ doff, int* __restrict__ bsum) {
    __shared__ int sh[256];
    int t = threadIdx.x;
    int i = blockIdx.x * 256 + t;
    int v = 0;
    if (i < NN) {
        const int* c = cnt + (size_t)i * RR;
#pragma unroll
        for (int r = 0; r < RR; ++r) v += c[r];
        dcount[i] = v;
    }
    sh[t] = v;
    __syncthreads();
    for (int s = 1; s < 256; s <<= 1) {
        int add = (t >= s) ? sh[t - s] : 0;
        __syncthreads();
        sh[t] += add;
        __syncthreads();
    }
    int incl = sh[t];
    if (i < NN) doff[i] = incl - v;
    if (t == 255) bsum[blockIdx.x] = incl;
}

__global__ void k_scan2(int* __restrict__ bsum, int nbv) {
    __shared__ int sh[256];
    int t = threadIdx.x;
    int v = (t < nbv) ? bsum[t] : 0;
    sh[t] = v;
    __syncthreads();
    for (int s = 1; s < 256; s <<= 1) {
        int add = (t >= s) ? sh[t - s] : 0;
        __syncthreads();
        sh[t] += add;
        __syncthreads();
    }
    if (t < nbv) bsum[t] = sh[t] - v;
}

__global__ void k_scan3(int* __restrict__ doff, const int* __restrict__ bsum) {
    int i = blockIdx.x * 256 + threadIdx.x;
    if (i < NN) doff[i] += bsum[blockIdx.x];
}

// records: .x = src | (rel<<16)  (src<65536, rel<50), .y = bits of a = 1/cnt(d,r)
__global__ void k_scatter(const int* __restrict__ src, const int* __restrict__ dst,
                          const int* __restrict__ et, const int* __restrict__ cnt,
                          const int* __restrict__ doff, int* __restrict__ cursor,
                          int2* __restrict__ ep2) {
    int e = blockIdx.x * 256 + threadIdx.x;
    if (e < EE) {
        int d = dst[e], r = et[e], s = src[e];
        int p = doff[d] + atomicAdd(&cursor[d], 1);
        float a = 1.0f / (float)cnt[d * RR + r];
        ep2[p] = make_int2(s | (r << 16), __float_as_int(a));
    }
}

// ---------------- degree counting-sort (descending) for wave balance ----------
// LDS-aggregated two-level histograms: R3's flat version did 50K device atomics
// onto ~40 hot bins (~300 us of serialized same-address atomics). Now each
// block aggregates in LDS first; global atomics <= 256 per block (1 per bin).

__global__ void k_deghist(const int* __restrict__ dcount, int* __restrict__ dbin) {
    __shared__ int lh[256];
    int t = threadIdx.x;
    int i = blockIdx.x * 256 + t;
    lh[t] = 0;
    __syncthreads();
    if (i < NN) {
        int d = dcount[i]; d = (d > 255) ? 255 : d;
        atomicAdd(&lh[255 - d], 1);          // LDS atomic
    }
    __syncthreads();
    if (lh[t]) atomicAdd(&dbin[t], lh[t]);   // 1 global atomic per bin per block
}

__global__ void k_degscan(int* __restrict__ dbin) {   // exclusive scan of 256
    __shared__ int sh[256];
    int t = threadIdx.x;
    int v = dbin[t];
    sh[t] = v;
    __syncthreads();
    for (int s = 1; s < 256; s <<= 1) {
        int add = (t >= s) ? sh[t - s] : 0;
        __syncthreads();
        sh[t] += add;
        __syncthreads();
    }
    dbin[t] = sh[t] - v;
}

__global__ void k_degscatter(const int* __restrict__ dcount, const int* __restrict__ dbin,
                             int* __restrict__ dcur, int* __restrict__ order) {
    __shared__ int lh[256], lbase[256];
    int t = threadIdx.x;
    int i = blockIdx.x * 256 + t;
    lh[t] = 0;
    __syncthreads();
    int b = 0, lpos = 0;
    if (i < NN) {
        int d = dcount[i]; d = (d > 255) ? 255 : d;
        b = 255 - d;
        lpos = atomicAdd(&lh[b], 1);         // LDS atomic
    }
    __syncthreads();
    lbase[t] = lh[t] ? atomicAdd(&dcur[t], lh[t]) : 0;  // 1 global atomic per bin
    __syncthreads();
    if (i < NN) order[dbin[b] + lbase[b] + lpos] = i;
}

__global__ void k_cast_x(const float* __restrict__ x, __hip_bfloat16* __restrict__ h) {
    int i = blockIdx.x * 256 + threadIdx.x;
    if (i < NN * DIN) h[i] = __float2bfloat16(x[i]);
}

// all 3 layers' comp [R,30] fp32 -> padded f16 [3][R,32]
__global__ void k_prep_comp3(const float* __restrict__ c0, const float* __restrict__ c1,
                             const float* __restrict__ c2, __half* __restrict__ cp) {
    int idx = blockIdx.x * 256 + threadIdx.x;
    if (idx < 3 * RR * CPAD) {
        int l = idx / (RR * CPAD);
        int rem = idx - l * (RR * CPAD);
        int r = rem / CPAD, i = rem - r * CPAD;
        const float* c = (l == 0) ? c0 : (l == 1) ? c1 : c2;
        cp[idx] = (i < BB) ? __float2half(c[r * BB + i]) : __float2half(0.f);
    }
}

// all 3 layers' transposed bf16 weights:
// wt rows [0,64): layer0; [64,128): layer1; [128,144): layer2 (dout=8, 16 padded rows)
__global__ void k_prep_w3(const float* __restrict__ b0, const float* __restrict__ r0,
                          const float* __restrict__ b1, const float* __restrict__ r1,
                          const float* __restrict__ b2, const float* __restrict__ r2,
                          short* __restrict__ wt) {
    int idx = blockIdx.x * 256 + threadIdx.x;
    if (idx >= 144 * KTOT) return;
    int row = idx / KTOT, k = idx - row * KTOT;
    const float* bs; const float* rt; int o, dout;
    if (row < 64)       { bs = b0; rt = r0; o = row;        dout = 64; }
    else if (row < 128) { bs = b1; rt = r1; o = row - 64;   dout = 64; }
    else                { bs = b2; rt = r2; o = row - 128;  dout = 8;  }
    float v = 0.f;
    if (o < dout)
        v = (k < BB * DIN) ? bs[k * dout + o] : rt[(k - BB * DIN) * dout + o];
    __hip_bfloat16 hb = __float2bfloat16(v);
    wt[idx] = *reinterpret_cast<const short*>(&hb);
}

// ---------------- fused per-layer kernel ----------------
// 1024 threads = 16 waves, 2 blocks/CU (LDS-capped) -> 32 waves/CU.
// R2 evidence: throughput ~ resident waves (latency-bound). So keep 32 waves/CU
// and attack the per-wave critical path instead:
//  * f16 packed accumulation (v_pk_fma_f16): acc 32->16 VGPRs, FMA count
//    32->16 per edge, comp row 128->64 B.
//  * freed VGPRs -> 3-chunk-deep gather pipeline (12 edge-gathers in flight).
//  * masked ghost records (a=0, src=0) instead of a serial tail loop.
// Wave wv owns degree-sorted node order[node0+wv] (balanced barriers).
// Phase 2 unchanged: MFMA 16x16x32 bf16 over K=1984.

// load+mask 4 records of chunk u (ghost edges get src=0, a=0 -> exact no-op)
#define LOADREC(u, q0, q1, q2, q3) do {                                         \
    const int _u  = (u);                                                        \
    const int _b  = beg + 4 * _u;                                               \
    const int _rm = cnt - 4 * _u;                                               \
    q0 = ep2[_b];     q1 = ep2[_b + 1];                                         \
    q2 = ep2[_b + 2]; q3 = ep2[_b + 3];                                         \
    q0.x = (_rm > 0) ? q0.x : 0;  q0.y = (_rm > 0) ? q0.y : 0;                  \
    q1.x = (_rm > 1) ? q1.x : 0;  q1.y = (_rm > 1) ? q1.y : 0;                  \
    q2.x = (_rm > 2) ? q2.x : 0;  q2.y = (_rm > 2) ? q2.y : 0;                  \
    q3.x = (_rm > 3) ? q3.x : 0;  q3.y = (_rm > 3) ? q3.y : 0;                  \
} while (0)

// issue gather for one record (raw bf16 bits; cvt deferred to FMA site)
#define GATH(q) ((unsigned)xin16[(RFL((q).x) & 0xFFFF) * DIN + lane])

// one edge's rank-1 update into __half2 ACC[16] (comp f16 row, 4x int4 loads)
#define EDGE_FMA(q, g, ACC) do {                                                \
    const int   _sx = RFL((q).x);                                               \
    const float _a  = __int_as_float(RFL((q).y));                               \
    const int4* _cr = (const int4*)(compH + (_sx >> 16) * CPAD);                \
    int4 _m0 = _cr[0], _m1 = _cr[1], _m2 = _cr[2], _m3 = _cr[3];                \
    const float _xvf = __uint_as_float((g) << 16) * _a;                         \
    const __half _xh = __float2half(_xvf);                                      \
    const __half2 _xv2 = __halves2half2(_xh, _xh);                              \
    const __half2* _p0 = reinterpret_cast<const __half2*>(&_m0);                \
    const __half2* _p1 = reinterpret_cast<const __half2*>(&_m1);                \
    const __half2* _p2 = reinterpret_cast<const __half2*>(&_m2);                \
    const __half2* _p3 = reinterpret_cast<const __half2*>(&_m3);                \
    ACC[0]  = __hfma2(_p0[0], _xv2, ACC[0]);                                    \
    ACC[1]  = __hfma2(_p0[1], _xv2, ACC[1]);                                    \
    ACC[2]  = __hfma2(_p0[2], _xv2, ACC[2]);                                    \
    ACC[3]  = __hfma2(_p0[3], _xv2, ACC[3]);                                    \
    ACC[4]  = __hfma2(_p1[0], _xv2, ACC[4]);                                    \
    ACC[5]  = __hfma2(_p1[1], _xv2, ACC[5]);                                    \
    ACC[6]  = __hfma2(_p1[2], _xv2, ACC[6]);                                    \
    ACC[7]  = __hfma2(_p1[3], _xv2, ACC[7]);                                    \
    ACC[8]  = __hfma2(_p2[0], _xv2, ACC[8]);                                    \
    ACC[9]  = __hfma2(_p2[1], _xv2, ACC[9]);                                    \
    ACC[10] = __hfma2(_p2[2], _xv2, ACC[10]);                                   \
    ACC[11] = __hfma2(_p2[3], _xv2, ACC[11]);                                   \
    ACC[12] = __hfma2(_p3[0], _xv2, ACC[12]);                                   \
    ACC[13] = __hfma2(_p3[1], _xv2, ACC[13]);                                   \
    ACC[14] = __hfma2(_p3[2], _xv2, ACC[14]);                                   \
    ACC[15] = __hfma2(_p3[3], _xv2, ACC[15]);                                   \
} while (0)

template <int DOUT, bool RELU>
__global__ __launch_bounds__(1024, 8)
void k_fused(const __hip_bfloat16* __restrict__ xin,
             const int2* __restrict__ ep2,
             const int* __restrict__ doff, const int* __restrict__ dcount,
             const int* __restrict__ order,
             const __half* __restrict__ compH,   // [R, 32] f16 padded
             const short* __restrict__ Wt,       // [DPAD][KTOT] bf16 (transposed)
             const float* __restrict__ bias,     // [DOUT]
             void* __restrict__ outp) {
    __shared__ __align__(16) char smem_raw[NBW * ROWE * 2];   // 63744 B
    auto t_tile = reinterpret_cast<__hip_bfloat16(*)[ROWE]>(smem_raw);
    const unsigned short* xin16 = reinterpret_cast<const unsigned short*>(xin);
    const int tid  = threadIdx.x;
    const int lane = tid & 63;
    const int wv   = RFL(tid >> 6);          // 0..15
    const int node0 = blockIdx.x * NBW;

    // ---- phase 1: one node per wave, 3-deep pipelined 4-edge chunks ----
    {
        const int j = wv;
        const int n = RFL(order[node0 + j]);
        __half2 acc[16];
#pragma unroll
        for (int u = 0; u < 16; ++u) acc[u] = __halves2half2(__float2half(0.f), __float2half(0.f));
        const int beg = RFL(doff[n]), cnt = RFL(dcount[n]);
        const int nch = (cnt + 3) >> 2;       // masked chunks, no tail loop

        if (nch > 0) {
            // records for chunks 0,1,2 (clamped)
            int2 c0, c1, c2, c3, n0, n1, n2, n3, p0, p1, p2, p3;
            LOADREC(0, c0, c1, c2, c3);
            { const int u1 = (1 < nch) ? 1 : (nch - 1); LOADREC(u1, n0, n1, n2, n3); }
            { const int u2 = (2 < nch) ? 2 : (nch - 1); LOADREC(u2, p0, p1, p2, p3); }
            // gathers for chunks 0,1,2 (12 in flight)
            unsigned g0 = GATH(c0), g1 = GATH(c1), g2 = GATH(c2), g3 = GATH(c3);
            unsigned h0 = GATH(n0), h1 = GATH(n1), h2 = GATH(n2), h3 = GATH(n3);
            unsigned i0 = GATH(p0), i1 = GATH(p1), i2 = GATH(p2), i3 = GATH(p3);

            for (int c = 0; c < nch; ++c) {
                // prefetch records for chunk c+3 (clamped; uniform s_load)
                int2 q0, q1, q2, q3;
                { const int u3 = (c + 3 < nch) ? (c + 3) : (nch - 1);
                  LOADREC(u3, q0, q1, q2, q3); }
                // FMA chunk c (waits only on chunk c's gathers; h,i stay in flight)
                EDGE_FMA(c0, g0, acc); EDGE_FMA(c1, g1, acc);
                EDGE_FMA(c2, g2, acc); EDGE_FMA(c3, g3, acc);
                // issue gathers for chunk c+3 (records just loaded)
                unsigned w0 = GATH(q0), w1 = GATH(q1), w2 = GATH(q2), w3 = GATH(q3);
                // rotate pipeline
                c0 = n0; c1 = n1; c2 = n2; c3 = n3;
                n0 = p0; n1 = p1; n2 = p2; n3 = p3;
                p0 = q0; p1 = q1; p2 = q2; p3 = q3;
                g0 = h0; g1 = h1; g2 = h2; g3 = h3;
                h0 = i0; h1 = i1; h2 = i2; h3 = i3;
                i0 = w0; i1 = w1; i2 = w2; i3 = w3;
            }
        }
        const float xself = __bfloat162float(xin[n * DIN + lane]);
#pragma unroll
        for (int b = 0; b < BB; ++b) {
            const float v = (b & 1) ? __high2float(acc[b >> 1]) : __low2float(acc[b >> 1]);
            t_tile[j][b * DIN + lane] = __float2bfloat16(v);
        }
        t_tile[j][BB * DIN + lane] = __float2bfloat16(xself);
    }
    __syncthreads();

    // ---- phase 2: MFMA 16x16x32 bf16, K = 1984 (62 steps) over 16 waves ----
    const int m = lane & 15;
    const int q = lane >> 4;
    int kk0, nsteps, col_base, kpart;
    if (DOUT == 64) {
        kpart = wv >> 2;                 // 0..3
        col_base = (wv & 3) * 16;
        kk0    = (kpart <= 1) ? kpart * 16 : (kpart == 2 ? 32 : 47);
        nsteps = (kpart <= 1) ? 16 : 15;
    } else {
        kpart = wv;                      // 0..15
        col_base = 0;
        kk0    = (kpart < 14) ? kpart * 4 : (kpart == 14 ? 56 : 59);
        nsteps = (kpart < 14) ? 4 : 3;
    }
    const __hip_bfloat16* arow = &t_tile[m][q * 8];
    const short* brow = Wt + (size_t)(col_base + m) * KTOT + q * 8;

    floatx4 acc0 = {0.f, 0.f, 0.f, 0.f};
    floatx4 acc1 = {0.f, 0.f, 0.f, 0.f};
    int s = 0;
    for (; s + 2 <= nsteps; s += 2) {
        const int kk = kk0 + s;
        short8 a0 = *reinterpret_cast<const short8*>(arow + kk * 32);
        short8 b0 = *reinterpret_cast<const short8*>(brow + kk * 32);
        short8 a1 = *reinterpret_cast<const short8*>(arow + (kk + 1) * 32);
        short8 b1 = *reinterpret_cast<const short8*>(brow + (kk + 1) * 32);
        acc0 = __builtin_amdgcn_mfma_f32_16x16x32_bf16(a0, b0, acc0, 0, 0, 0);
        acc1 = __builtin_amdgcn_mfma_f32_16x16x32_bf16(a1, b1, acc1, 0, 0, 0);
    }
    if (s < nsteps) {
        const int kk = kk0 + s;
        short8 a0 = *reinterpret_cast<const short8*>(arow + kk * 32);
        short8 b0 = *reinterpret_cast<const short8*>(brow + kk * 32);
        acc0 = __builtin_amdgcn_mfma_f32_16x16x32_bf16(a0, b0, acc0, 0, 0, 0);
    }
    floatx4 P = acc0 + acc1;

    __syncthreads();                       // all t_tile reads done
    float* red = (float*)smem_raw;         // reuse LDS; stride-6 layout

    if (DOUT == 64) {
        // 4 K-parts per col group; parts 1..3 write, part 0 reduces
        if (kpart > 0) {
            const int slot = (wv & 3) * 3 + (kpart - 1);   // 0..11
            const int off = (slot * 64 + lane) * 6;
            red[off] = P[0]; red[off + 1] = P[1]; red[off + 2] = P[2]; red[off + 3] = P[3];
        }
        __syncthreads();
        if (kpart == 0) {
#pragma unroll
            for (int t = 0; t < 3; ++t) {
                const int off = (((wv & 3) * 3 + t) * 64 + lane) * 6;
                P[0] += red[off]; P[1] += red[off + 1];
                P[2] += red[off + 2]; P[3] += red[off + 3];
            }
            const int o = col_base + m;
            const float bi = bias[o];
#pragma unroll
            for (int r = 0; r < 4; ++r) {
                const int n = order[node0 + q * 4 + r];
                float v = P[r] + bi;
                if (RELU) {
                    v = fmaxf(v, 0.f);
                    reinterpret_cast<__hip_bfloat16*>(outp)[(size_t)n * DOUT + o] =
                        __float2bfloat16(v);
                } else {
                    reinterpret_cast<float*>(outp)[(size_t)n * DOUT + o] = v;
                }
            }
        }
    } else {
        if (kpart > 0) {
            const int off = ((kpart - 1) * 64 + lane) * 6;
            red[off] = P[0]; red[off + 1] = P[1]; red[off + 2] = P[2]; red[off + 3] = P[3];
        }
        __syncthreads();
        if (kpart == 0) {
#pragma unroll
            for (int w = 0; w < 15; ++w) {
                const int off = (w * 64 + lane) * 6;
                P[0] += red[off]; P[1] += red[off + 1];
                P[2] += red[off + 2]; P[3] += red[off + 3];
            }
            if (m < DOUT) {
                const int o = m;
                const float bi = bias[o];
#pragma unroll
                for (int r = 0; r < 4; ++r) {
                    const int n = order[node0 + q * 4 + r];
                    reinterpret_cast<float*>(outp)[(size_t)n * DOUT + o] = P[r] + bi;
                }
            }
        }
    }
}

// ---------------- log_softmax over C=8 ----------------
__global__ void k_lsm(const float* __restrict__ pre, float* __restrict__ out) {
    int n = blockIdx.x * 256 + threadIdx.x;
    if (n < NN) {
        float v[8];
        float mx = -1e30f;
#pragma unroll
        for (int c = 0; c < 8; ++c) { v[c] = pre[n * 8 + c]; mx = fmaxf(mx, v[c]); }
        float s = 0.f;
#pragma unroll
        for (int c = 0; c < 8; ++c) s += expf(v[c] - mx);
        float ls = logf(s);
#pragma unroll
        for (int c = 0; c < 8; ++c) out[n * 8 + c] = v[c] - mx - ls;
    }
}

// ---------------- launch ----------------
extern "C" void kernel_launch(void* const* d_in, const int* in_sizes, int n_in,
                              void* d_out, int out_size, void* d_ws, size_t ws_size,
                              hipStream_t stream) {
    const float* x     = (const float*)d_in[0];
    const int*   eidx  = (const int*)d_in[1];
    const int*   etype = (const int*)d_in[2];
    const float* bases0 = (const float*)d_in[3];
    const float* comp0  = (const float*)d_in[4];
    const float* root0  = (const float*)d_in[5];
    const float* bias0  = (const float*)d_in[6];
    const float* bases1 = (const float*)d_in[7];
    const float* comp1  = (const float*)d_in[8];
    const float* root1  = (const float*)d_in[9];
    const float* bias1  = (const float*)d_in[10];
    const float* bases2 = (const float*)d_in[11];
    const float* comp2  = (const float*)d_in[12];
    const float* root2  = (const float*)d_in[13];
    const float* bias2  = (const float*)d_in[14];
    const int* srcp = eidx;
    const int* dstp = eidx + EE;

    char* p = (char*)d_ws;
    auto carve = [&](size_t bytes) -> char* {
        char* r = p;
        p += (bytes + 255) & ~(size_t)255;
        return r;
    };
    int*  cnt    = (int*)carve((size_t)NN * RR * sizeof(int));   // 10 MB
    int*  dcount = (int*)carve((size_t)NN * sizeof(int));
    int*  cursor = (int*)carve((size_t)NN * sizeof(int));
    int*  doff   = (int*)carve((size_t)NN * sizeof(int));
    int*  bsum   = (int*)carve(256 * sizeof(int));
    int*  dbin   = (int*)carve(256 * sizeof(int));
    int*  dcur   = (int*)carve(256 * sizeof(int));
    int*  order  = (int*)carve((size_t)NN * sizeof(int));
    int2* ep2    = (int2*)carve((size_t)(EE + 16) * sizeof(int2)); // 8 MB (+pad)
    __hip_bfloat16* h0 = (__hip_bfloat16*)carve((size_t)NN * DIN * 2);
    __hip_bfloat16* h1 = (__hip_bfloat16*)carve((size_t)NN * DIN * 2);
    __hip_bfloat16* h2 = (__hip_bfloat16*)carve((size_t)NN * DIN * 2);
    float* pre = (float*)carve((size_t)NN * 8 * sizeof(float));
    short* wtA = (short*)carve((size_t)144 * KTOT * sizeof(short));  // 3 layers stacked
    __half* cpA = (__half*)carve((size_t)3 * RR * CPAD * sizeof(__half));

    // cnt, dcount, cursor are adjacent in the carve order -> one memset
    hipMemsetAsync(cnt, 0, (size_t)NN * (RR + 2) * sizeof(int) + 512, stream);
    // dbin, dcur adjacent (each carved to 1024 B)
    hipMemsetAsync(dbin, 0, 2048, stream);

    const int EB = (EE + 255) / 256;   // 3907
    const int NB = (NN + 255) / 256;   // 196
    k_hist<<<EB, 256, 0, stream>>>(dstp, etype, cnt);
    k_scan1<<<NB, 256, 0, stream>>>(cnt, dcount, doff, bsum);
    k_scan2<<<1, 256, 0, stream>>>(bsum, NB);
    k_scan3<<<NB, 256, 0, stream>>>(doff, bsum);
    k_scatter<<<EB, 256, 0, stream>>>(srcp, dstp, etype, cnt, doff, cursor, ep2);
    k_deghist<<<NB, 256, 0, stream>>>(dcount, dbin);
    k_degscan<<<1, 256, 0, stream>>>(dbin);
    k_degscatter<<<NB, 256, 0, stream>>>(dcount, dbin, dcur, order);
    k_cast_x<<<(NN * DIN + 255) / 256, 256, 0, stream>>>(x, h0);
    k_prep_comp3<<<(3 * RR * CPAD + 255) / 256, 256, 0, stream>>>(comp0, comp1, comp2, cpA);
    k_prep_w3<<<(144 * KTOT + 255) / 256, 256, 0, stream>>>(bases0, root0, bases1, root1,
                                                            bases2, root2, wtA);

    short* wt0 = wtA;
    short* wt1 = wtA + (size_t)64 * KTOT;
    short* wt2 = wtA + (size_t)128 * KTOT;
    __half* cp0 = cpA;
    __half* cp1 = cpA + RR * CPAD;
    __half* cp2 = cpA + 2 * RR * CPAD;

    const int NF = NN / NBW;   // 3125 (exact)
    k_fused<64, true ><<<NF, 1024, 0, stream>>>(h0, ep2, doff, dcount, order, cp0, wt0, bias0, (void*)h1);
    k_fused<64, true ><<<NF, 1024, 0, stream>>>(h1, ep2, doff, dcount, order, cp1, wt1, bias1, (void*)h2);
    k_fused<8,  false><<<NF, 1024, 0, stream>>>(h2, ep2, doff, dcount, order, cp2, wt2, bias2, (void*)pre);
    k_lsm<<<NB, 256, 0, stream>>>(pre, (float*)d_out);
}

// Round 5
// 547.379 us; speedup vs baseline: 1.5887x; 1.0713x over previous
//
#include <hip/hip_runtime.h>
#include <hip/hip_bf16.h>
#include <hip/hip_fp16.h>
#include <stdint.h>

// Problem constants (fixed by the reference)
#define NN   50000
#define RR   50
#define BB   30
#define DIN  64
#define EE   1000000
#define KTOT (BB*DIN + DIN)   // 1984 = 62*32
#define NBW  16               // nodes per workgroup; 50000 = 3125*16 exactly
#define ROWE (KTOT + 8)       // padded LDS row: 1992 elems (3984 B)
#define CPAD 32               // comp row padded 30 -> 32 halves (64 B)
#define EPAD (EE + 4*NN + 16) // ep2 entries incl. per-node 4-alignment ghosts

typedef __attribute__((ext_vector_type(8))) short short8;
typedef __attribute__((ext_vector_type(4))) float floatx4;

#define RFL(x) __builtin_amdgcn_readfirstlane(x)

// ---------------- preprocessing: counting sort of edges by dst ----------------

__global__ void k_hist(const int* __restrict__ dst, const int* __restrict__ et,
                       int* __restrict__ cnt) {
    int e = blockIdx.x * 256 + threadIdx.x;
    if (e < EE) {
        int d = dst[e], r = et[e];
        atomicAdd(&cnt[d * RR + r], 1);
    }
}

// derive dcount from cnt rows; PAD each node's segment to a multiple of 4
// (ghost slots stay all-zero from the ep2 memset -> exact no-op edges, and
// every chunk becomes two aligned int4 record loads, no masking).
__global__ void k_scan1(const int* __restrict__ cnt, int* __restrict__ dcount,
                        int* __restrict__ doff, int* __restrict__ bsum) {
    __shared__ int sh[256];
    int t = threadIdx.x;
    int i = blockIdx.x * 256 + t;
    int vp = 0;
    if (i < NN) {
        const int* c = cnt + (size_t)i * RR;
        int v = 0;
#pragma unroll
        for (int r = 0; r < RR; ++r) v += c[r];
        vp = (v + 3) & ~3;                 // padded count
        dcount[i] = vp;
    }
    sh[t] = vp;
    __syncthreads();
    for (int s = 1; s < 256; s <<= 1) {
        int add = (t >= s) ? sh[t - s] : 0;
        __syncthreads();
        sh[t] += add;
        __syncthreads();
    }
    int incl = sh[t];
    if (i < NN) doff[i] = incl - vp;
    if (t == 255) bsum[blockIdx.x] = incl;
}

__global__ void k_scan2(int* __restrict__ bsum, int nbv) {
    __shared__ int sh[256];
    int t = threadIdx.x;
    int v = (t < nbv) ? bsum[t] : 0;
    sh[t] = v;
    __syncthreads();
    for (int s = 1; s < 256; s <<= 1) {
        int add = (t >= s) ? sh[t - s] : 0;
        __syncthreads();
        sh[t] += add;
        __syncthreads();
    }
    if (t < nbv) bsum[t] = sh[t] - v;
}

__global__ void k_scan3(int* __restrict__ doff, const int* __restrict__ bsum) {
    int i = blockIdx.x * 256 + threadIdx.x;
    if (i < NN) doff[i] += bsum[blockIdx.x];
}

// records: .x = src | (rel<<16)  (src<65536, rel<50), .y = bits of a = 1/cnt(d,r)
__global__ void k_scatter(const int* __restrict__ src, const int* __restrict__ dst,
                          const int* __restrict__ et, const int* __restrict__ cnt,
                          const int* __restrict__ doff, int* __restrict__ cursor,
                          int2* __restrict__ ep2) {
    int e = blockIdx.x * 256 + threadIdx.x;
    if (e < EE) {
        int d = dst[e], r = et[e], s = src[e];
        int p = doff[d] + atomicAdd(&cursor[d], 1);
        float a = 1.0f / (float)cnt[d * RR + r];
        ep2[p] = make_int2(s | (r << 16), __float_as_int(a));
    }
}

// ---------------- degree counting-sort (descending) for wave balance ----------
// LDS-aggregated two-level histograms (<=256 global atomics per block).

__global__ void k_deghist(const int* __restrict__ dcount, int* __restrict__ dbin) {
    __shared__ int lh[256];
    int t = threadIdx.x;
    int i = blockIdx.x * 256 + t;
    lh[t] = 0;
    __syncthreads();
    if (i < NN) {
        int d = dcount[i]; d = (d > 255) ? 255 : d;
        atomicAdd(&lh[255 - d], 1);          // LDS atomic
    }
    __syncthreads();
    if (lh[t]) atomicAdd(&dbin[t], lh[t]);   // 1 global atomic per bin per block
}

__global__ void k_degscan(int* __restrict__ dbin) {   // exclusive scan of 256
    __shared__ int sh[256];
    int t = threadIdx.x;
    int v = dbin[t];
    sh[t] = v;
    __syncthreads();
    for (int s = 1; s < 256; s <<= 1) {
        int add = (t >= s) ? sh[t - s] : 0;
        __syncthreads();
        sh[t] += add;
        __syncthreads();
    }
    dbin[t] = sh[t] - v;
}

__global__ void k_degscatter(const int* __restrict__ dcount, const int* __restrict__ dbin,
                             int* __restrict__ dcur, int* __restrict__ order) {
    __shared__ int lh[256], lbase[256];
    int t = threadIdx.x;
    int i = blockIdx.x * 256 + t;
    lh[t] = 0;
    __syncthreads();
    int b = 0, lpos = 0;
    if (i < NN) {
        int d = dcount[i]; d = (d > 255) ? 255 : d;
        b = 255 - d;
        lpos = atomicAdd(&lh[b], 1);         // LDS atomic
    }
    __syncthreads();
    lbase[t] = lh[t] ? atomicAdd(&dcur[t], lh[t]) : 0;  // 1 global atomic per bin
    __syncthreads();
    if (i < NN) order[dbin[b] + lbase[b] + lpos] = i;
}

__global__ void k_cast_x(const float* __restrict__ x, __hip_bfloat16* __restrict__ h) {
    int i = blockIdx.x * 256 + threadIdx.x;
    if (i < NN * DIN) h[i] = __float2bfloat16(x[i]);
}

// all 3 layers' comp [R,30] fp32 -> padded f16 [3][R,32]
__global__ void k_prep_comp3(const float* __restrict__ c0, const float* __restrict__ c1,
                             const float* __restrict__ c2, __half* __restrict__ cp) {
    int idx = blockIdx.x * 256 + threadIdx.x;
    if (idx < 3 * RR * CPAD) {
        int l = idx / (RR * CPAD);
        int rem = idx - l * (RR * CPAD);
        int r = rem / CPAD, i = rem - r * CPAD;
        const float* c = (l == 0) ? c0 : (l == 1) ? c1 : c2;
        cp[idx] = (i < BB) ? __float2half(c[r * BB + i]) : __float2half(0.f);
    }
}

// all 3 layers' transposed bf16 weights:
// wt rows [0,64): layer0; [64,128): layer1; [128,144): layer2 (dout=8, 16 padded rows)
__global__ void k_prep_w3(const float* __restrict__ b0, const float* __restrict__ r0,
                          const float* __restrict__ b1, const float* __restrict__ r1,
                          const float* __restrict__ b2, const float* __restrict__ r2,
                          short* __restrict__ wt) {
    int idx = blockIdx.x * 256 + threadIdx.x;
    if (idx >= 144 * KTOT) return;
    int row = idx / KTOT, k = idx - row * KTOT;
    const float* bs; const float* rt; int o, dout;
    if (row < 64)       { bs = b0; rt = r0; o = row;        dout = 64; }
    else if (row < 128) { bs = b1; rt = r1; o = row - 64;   dout = 64; }
    else                { bs = b2; rt = r2; o = row - 128;  dout = 8;  }
    float v = 0.f;
    if (o < dout)
        v = (k < BB * DIN) ? bs[k * dout + o] : rt[(k - BB * DIN) * dout + o];
    __hip_bfloat16 hb = __float2bfloat16(v);
    wt[idx] = *reinterpret_cast<const short*>(&hb);
}

// ---------------- fused per-layer kernel ----------------
// 1024 threads = 16 waves, 2 blocks/CU (LDS-capped) -> 32 waves/CU.
// Phase-1 schedule (the R4 post-mortem fix): never consume a load in the
// iteration that issued it.
//   records for chunk t+3..t+4 in flight (2 stages, ping-pong via unroll-2);
//   RFL+gather-issue for chunk t+3 at iter t (record distance 2 iters);
//   FMA chunk t uses gathers issued at iter t-3 (gather distance 3 iters).
// Segments are 4-aligned with all-zero ghost records (a=0 -> exact no-op),
// so chunk records are two aligned int4 loads and there is no masking/tail.
// f16 packed accumulation (v_pk_fma_f16), 16 hfma2 per edge.
// Phase 2 unchanged: MFMA 16x16x32 bf16 over K=1984.

struct RecS { int x0, a0i, x1, a1i, x2, a2i, x3, a3i; };   // wave-uniform scalars

#define LOADREC4(u, VA, VB) do {                                                \
    const int _u = ((u) < nch) ? (u) : (nch - 1);                               \
    const int _i4 = base4 + 2 * _u;                                             \
    VA = ep4[_i4]; VB = ep4[_i4 + 1];                                           \
} while (0)

#define RFLREC(VA, VB, S) do {                                                  \
    S.x0 = RFL((VA).x); S.a0i = RFL((VA).y);                                    \
    S.x1 = RFL((VA).z); S.a1i = RFL((VA).w);                                    \
    S.x2 = RFL((VB).x); S.a2i = RFL((VB).y);                                    \
    S.x3 = RFL((VB).z); S.a3i = RFL((VB).w);                                    \
} while (0)

#define GATH1(sx) ((unsigned)xin16[((sx) & 0xFFFF) * DIN + lane])

#define EDGE_FMA_H(_sx, _ai, _g, ACC) do {                                      \
    const int4* _cr = (const int4*)(compH + ((_sx) >> 16) * CPAD);              \
    int4 _m0 = _cr[0], _m1 = _cr[1], _m2 = _cr[2], _m3 = _cr[3];                \
    const float _xvf = __uint_as_float((unsigned)(_g) << 16) * __int_as_float(_ai); \
    const __half _xh = __float2half(_xvf);                                      \
    const __half2 _xv2 = __halves2half2(_xh, _xh);                              \
    const __half2* _p0 = reinterpret_cast<const __half2*>(&_m0);                \
    const __half2* _p1 = reinterpret_cast<const __half2*>(&_m1);                \
    const __half2* _p2 = reinterpret_cast<const __half2*>(&_m2);                \
    const __half2* _p3 = reinterpret_cast<const __half2*>(&_m3);                \
    ACC[0]  = __hfma2(_p0[0], _xv2, ACC[0]);                                    \
    ACC[1]  = __hfma2(_p0[1], _xv2, ACC[1]);                                    \
    ACC[2]  = __hfma2(_p0[2], _xv2, ACC[2]);                                    \
    ACC[3]  = __hfma2(_p0[3], _xv2, ACC[3]);                                    \
    ACC[4]  = __hfma2(_p1[0], _xv2, ACC[4]);                                    \
    ACC[5]  = __hfma2(_p1[1], _xv2, ACC[5]);                                    \
    ACC[6]  = __hfma2(_p1[2], _xv2, ACC[6]);                                    \
    ACC[7]  = __hfma2(_p1[3], _xv2, ACC[7]);                                    \
    ACC[8]  = __hfma2(_p2[0], _xv2, ACC[8]);                                    \
    ACC[9]  = __hfma2(_p2[1], _xv2, ACC[9]);                                    \
    ACC[10] = __hfma2(_p2[2], _xv2, ACC[10]);                                   \
    ACC[11] = __hfma2(_p2[3], _xv2, ACC[11]);                                   \
    ACC[12] = __hfma2(_p3[0], _xv2, ACC[12]);                                   \
    ACC[13] = __hfma2(_p3[1], _xv2, ACC[13]);                                   \
    ACC[14] = __hfma2(_p3[2], _xv2, ACC[14]);                                   \
    ACC[15] = __hfma2(_p3[3], _xv2, ACC[15]);                                   \
} while (0)

// one pipeline iteration: FMA chunk tt; gather chunk tt+3; load records tt+5
#define ITER(tt, VA, VB) do {                                                   \
    RecS s3; RFLREC(VA, VB, s3);                                                \
    LOADREC4((tt) + 5, VA, VB);                                                 \
    unsigned w0 = GATH1(s3.x0), w1 = GATH1(s3.x1);                              \
    unsigned w2 = GATH1(s3.x2), w3 = GATH1(s3.x3);                              \
    EDGE_FMA_H(s0.x0, s0.a0i, g0, acc); EDGE_FMA_H(s0.x1, s0.a1i, g1, acc);     \
    EDGE_FMA_H(s0.x2, s0.a2i, g2, acc); EDGE_FMA_H(s0.x3, s0.a3i, g3, acc);     \
    s0 = s1; s1 = s2; s2 = s3;                                                  \
    g0 = h0; g1 = h1; g2 = h2; g3 = h3;                                         \
    h0 = i0; h1 = i1; h2 = i2; h3 = i3;                                         \
    i0 = w0; i1 = w1; i2 = w2; i3 = w3;                                         \
} while (0)

template <int DOUT, bool RELU>
__global__ __launch_bounds__(1024, 8)
void k_fused(const __hip_bfloat16* __restrict__ xin,
             const int2* __restrict__ ep2,
             const int* __restrict__ doff, const int* __restrict__ dcount,
             const int* __restrict__ order,
             const __half* __restrict__ compH,   // [R, 32] f16 padded
             const short* __restrict__ Wt,       // [DPAD][KTOT] bf16 (transposed)
             const float* __restrict__ bias,     // [DOUT]
             void* __restrict__ outp) {
    __shared__ __align__(16) char smem_raw[NBW * ROWE * 2];   // 63744 B
    auto t_tile = reinterpret_cast<__hip_bfloat16(*)[ROWE]>(smem_raw);
    const unsigned short* xin16 = reinterpret_cast<const unsigned short*>(xin);
    const int tid  = threadIdx.x;
    const int lane = tid & 63;
    const int wv   = RFL(tid >> 6);          // 0..15
    const int node0 = blockIdx.x * NBW;

    // ---- phase 1: one node per wave, deep pipelined 4-edge chunks ----
    {
        const int j = wv;
        const int n = RFL(order[node0 + j]);
        __half2 acc[16];
#pragma unroll
        for (int u = 0; u < 16; ++u)
            acc[u] = __halves2half2(__float2half(0.f), __float2half(0.f));
        const int beg = RFL(doff[n]);
        const int nch = RFL(dcount[n]) >> 2;   // padded count / 4, no tail

        if (nch > 0) {
            const int4* ep4 = reinterpret_cast<const int4*>(ep2);
            const int base4 = beg >> 1;        // beg is a multiple of 4 records
            int4 vaA, vbA, vaB, vbB;
            RecS s0, s1, s2;
            // prologue: fill 3 gather stages + 2 record stages
            LOADREC4(0, vaA, vbA);
            LOADREC4(1, vaB, vbB);
            RFLREC(vaA, vbA, s0);
            unsigned g0 = GATH1(s0.x0), g1 = GATH1(s0.x1);
            unsigned g2 = GATH1(s0.x2), g3 = GATH1(s0.x3);
            LOADREC4(2, vaA, vbA);
            RFLREC(vaB, vbB, s1);
            unsigned h0 = GATH1(s1.x0), h1 = GATH1(s1.x1);
            unsigned h2 = GATH1(s1.x2), h3 = GATH1(s1.x3);
            LOADREC4(3, vaB, vbB);
            RFLREC(vaA, vbA, s2);
            unsigned i0 = GATH1(s2.x0), i1 = GATH1(s2.x1);
            unsigned i2 = GATH1(s2.x2), i3 = GATH1(s2.x3);
            LOADREC4(4, vaA, vbA);
            // stages now: A = chunk 4 (in flight), B = chunk 3 (in flight)
            int t = 0;
            for (; t + 2 <= nch; t += 2) {
                ITER(t,     vaB, vbB);   // consumes chunk t+3, loads t+5 into B
                ITER(t + 1, vaA, vbA);   // consumes chunk t+4, loads t+6 into A
            }
            if (t < nch) ITER(t, vaB, vbB);
        }
        const float xself = __bfloat162float(xin[n * DIN + lane]);
#pragma unroll
        for (int b = 0; b < BB; ++b) {
            const float v = (b & 1) ? __high2float(acc[b >> 1]) : __low2float(acc[b >> 1]);
            t_tile[j][b * DIN + lane] = __float2bfloat16(v);
        }
        t_tile[j][BB * DIN + lane] = __float2bfloat16(xself);
    }
    __syncthreads();

    // ---- phase 2: MFMA 16x16x32 bf16, K = 1984 (62 steps) over 16 waves ----
    const int m = lane & 15;
    const int q = lane >> 4;
    int kk0, nsteps, col_base, kpart;
    if (DOUT == 64) {
        kpart = wv >> 2;                 // 0..3
        col_base = (wv & 3) * 16;
        kk0    = (kpart <= 1) ? kpart * 16 : (kpart == 2 ? 32 : 47);
        nsteps = (kpart <= 1) ? 16 : 15;
    } else {
        kpart = wv;                      // 0..15
        col_base = 0;
        kk0    = (kpart < 14) ? kpart * 4 : (kpart == 14 ? 56 : 59);
        nsteps = (kpart < 14) ? 4 : 3;
    }
    const __hip_bfloat16* arow = &t_tile[m][q * 8];
    const short* brow = Wt + (size_t)(col_base + m) * KTOT + q * 8;

    floatx4 acc0 = {0.f, 0.f, 0.f, 0.f};
    floatx4 acc1 = {0.f, 0.f, 0.f, 0.f};
    int s = 0;
    for (; s + 2 <= nsteps; s += 2) {
        const int kk = kk0 + s;
        short8 a0 = *reinterpret_cast<const short8*>(arow + kk * 32);
        short8 b0 = *reinterpret_cast<const short8*>(brow + kk * 32);
        short8 a1 = *reinterpret_cast<const short8*>(arow + (kk + 1) * 32);
        short8 b1 = *reinterpret_cast<const short8*>(brow + (kk + 1) * 32);
        acc0 = __builtin_amdgcn_mfma_f32_16x16x32_bf16(a0, b0, acc0, 0, 0, 0);
        acc1 = __builtin_amdgcn_mfma_f32_16x16x32_bf16(a1, b1, acc1, 0, 0, 0);
    }
    if (s < nsteps) {
        const int kk = kk0 + s;
        short8 a0 = *reinterpret_cast<const short8*>(arow + kk * 32);
        short8 b0 = *reinterpret_cast<const short8*>(brow + kk * 32);
        acc0 = __builtin_amdgcn_mfma_f32_16x16x32_bf16(a0, b0, acc0, 0, 0, 0);
    }
    floatx4 P = acc0 + acc1;

    __syncthreads();                       // all t_tile reads done
    float* red = (float*)smem_raw;         // reuse LDS; stride-6 layout

    if (DOUT == 64) {
        // 4 K-parts per col group; parts 1..3 write, part 0 reduces
        if (kpart > 0) {
            const int slot = (wv & 3) * 3 + (kpart - 1);   // 0..11
            const int off = (slot * 64 + lane) * 6;
            red[off] = P[0]; red[off + 1] = P[1]; red[off + 2] = P[2]; red[off + 3] = P[3];
        }
        __syncthreads();
        if (kpart == 0) {
#pragma unroll
            for (int t = 0; t < 3; ++t) {
                const int off = (((wv & 3) * 3 + t) * 64 + lane) * 6;
                P[0] += red[off]; P[1] += red[off + 1];
                P[2] += red[off + 2]; P[3] += red[off + 3];
            }
            const int o = col_base + m;
            const float bi = bias[o];
#pragma unroll
            for (int r = 0; r < 4; ++r) {
                const int n = order[node0 + q * 4 + r];
                float v = P[r] + bi;
                if (RELU) {
                    v = fmaxf(v, 0.f);
                    reinterpret_cast<__hip_bfloat16*>(outp)[(size_t)n * DOUT + o] =
                        __float2bfloat16(v);
                } else {
                    reinterpret_cast<float*>(outp)[(size_t)n * DOUT + o] = v;
                }
            }
        }
    } else {
        if (kpart > 0) {
            const int off = ((kpart - 1) * 64 + lane) * 6;
            red[off] = P[0]; red[off + 1] = P[1]; red[off + 2] = P[2]; red[off + 3] = P[3];
        }
        __syncthreads();
        if (kpart == 0) {
#pragma unroll
            for (int w = 0; w < 15; ++w) {
                const int off = (w * 64 + lane) * 6;
                P[0] += red[off]; P[1] += red[off + 1];
                P[2] += red[off + 2]; P[3] += red[off + 3];
            }
            if (m < DOUT) {
                const int o = m;
                const float bi = bias[o];
#pragma unroll
                for (int r = 0; r < 4; ++r) {
                    const int n = order[node0 + q * 4 + r];
                    reinterpret_cast<float*>(outp)[(size_t)n * DOUT + o] = P[r] + bi;
                }
            }
        }
    }
}

// ---------------- log_softmax over C=8 ----------------
__global__ void k_lsm(const float* __restrict__ pre, float* __restrict__ out) {
    int n = blockIdx.x * 256 + threadIdx.x;
    if (n < NN) {
        float v[8];
        float mx = -1e30f;
#pragma unroll
        for (int c = 0; c < 8; ++c) { v[c] = pre[n * 8 + c]; mx = fmaxf(mx, v[c]); }
        float s = 0.f;
#pragma unroll
        for (int c = 0; c < 8; ++c) s += expf(v[c] - mx);
        float ls = logf(s);
#pragma unroll
        for (int c = 0; c < 8; ++c) out[n * 8 + c] = v[c] - mx - ls;
    }
}

// ---------------- launch ----------------
extern "C" void kernel_launch(void* const* d_in, const int* in_sizes, int n_in,
                              void* d_out, int out_size, void* d_ws, size_t ws_size,
                              hipStream_t stream) {
    const float* x     = (const float*)d_in[0];
    const int*   eidx  = (const int*)d_in[1];
    const int*   etype = (const int*)d_in[2];
    const float* bases0 = (const float*)d_in[3];
    const float* comp0  = (const float*)d_in[4];
    const float* root0  = (const float*)d_in[5];
    const float* bias0  = (const float*)d_in[6];
    const float* bases1 = (const float*)d_in[7];
    const float* comp1  = (const float*)d_in[8];
    const float* root1  = (const float*)d_in[9];
    const float* bias1  = (const float*)d_in[10];
    const float* bases2 = (const float*)d_in[11];
    const float* comp2  = (const float*)d_in[12];
    const float* root2  = (const float*)d_in[13];
    const float* bias2  = (const float*)d_in[14];
    const int* srcp = eidx;
    const int* dstp = eidx + EE;

    char* p = (char*)d_ws;
    auto carve = [&](size_t bytes) -> char* {
        char* r = p;
        p += (bytes + 255) & ~(size_t)255;
        return r;
    };
    int*  cnt    = (int*)carve((size_t)NN * RR * sizeof(int));   // 10 MB
    int*  dcount = (int*)carve((size_t)NN * sizeof(int));
    int*  cursor = (int*)carve((size_t)NN * sizeof(int));
    int*  doff   = (int*)carve((size_t)NN * sizeof(int));
    int*  bsum   = (int*)carve(256 * sizeof(int));
    int*  dbin   = (int*)carve(256 * sizeof(int));
    int*  dcur   = (int*)carve(256 * sizeof(int));
    int*  order  = (int*)carve((size_t)NN * sizeof(int));
    int2* ep2    = (int2*)carve((size_t)EPAD * sizeof(int2));    // ~9.6 MB
    __hip_bfloat16* h0 = (__hip_bfloat16*)carve((size_t)NN * DIN * 2);
    __hip_bfloat16* h1 = (__hip_bfloat16*)carve((size_t)NN * DIN * 2);
    __hip_bfloat16* h2 = (__hip_bfloat16*)carve((size_t)NN * DIN * 2);
    float* pre = (float*)carve((size_t)NN * 8 * sizeof(float));
    short* wtA = (short*)carve((size_t)144 * KTOT * sizeof(short));  // 3 layers stacked
    __half* cpA = (__half*)carve((size_t)3 * RR * CPAD * sizeof(__half));

    // cnt, dcount, cursor are adjacent in the carve order -> one memset
    hipMemsetAsync(cnt, 0, (size_t)NN * (RR + 2) * sizeof(int) + 512, stream);
    // dbin, dcur adjacent (each carved to 1024 B)
    hipMemsetAsync(dbin, 0, 2048, stream);
    // ghost record slots must be zero (a=0 -> exact no-op edges)
    hipMemsetAsync(ep2, 0, (size_t)EPAD * sizeof(int2), stream);

    const int EB = (EE + 255) / 256;   // 3907
    const int NB = (NN + 255) / 256;   // 196
    k_hist<<<EB, 256, 0, stream>>>(dstp, etype, cnt);
    k_scan1<<<NB, 256, 0, stream>>>(cnt, dcount, doff, bsum);
    k_scan2<<<1, 256, 0, stream>>>(bsum, NB);
    k_scan3<<<NB, 256, 0, stream>>>(doff, bsum);
    k_scatter<<<EB, 256, 0, stream>>>(srcp, dstp, etype, cnt, doff, cursor, ep2);
    k_deghist<<<NB, 256, 0, stream>>>(dcount, dbin);
    k_degscan<<<1, 256, 0, stream>>>(dbin);
    k_degscatter<<<NB, 256, 0, stream>>>(dcount, dbin, dcur, order);
    k_cast_x<<<(NN * DIN + 255) / 256, 256, 0, stream>>>(x, h0);
    k_prep_comp3<<<(3 * RR * CPAD + 255) / 256, 256, 0, stream>>>(comp0, comp1, comp2, cpA);
    k_prep_w3<<<(144 * KTOT + 255) / 256, 256, 0, stream>>>(bases0, root0, bases1, root1,
                                                            bases2, root2, wtA);

    short* wt0 = wtA;
    short* wt1 = wtA + (size_t)64 * KTOT;
    short* wt2 = wtA + (size_t)128 * KTOT;
    __half* cp0 = cpA;
    __half* cp1 = cpA + RR * CPAD;
    __half* cp2 = cpA + 2 * RR * CPAD;

    const int NF = NN / NBW;   // 3125 (exact)
    k_fused<64, true ><<<NF, 1024, 0, stream>>>(h0, ep2, doff, dcount, order, cp0, wt0, bias0, (void*)h1);
    k_fused<64, true ><<<NF, 1024, 0, stream>>>(h1, ep2, doff, dcount, order, cp1, wt1, bias1, (void*)h2);
    k_fused<8,  false><<<NF, 1024, 0, stream>>>(h2, ep2, doff, dcount, order, cp2, wt2, bias2, (void*)pre);
    k_lsm<<<NB, 256, 0, stream>>>(pre, (float*)d_out);
}